// Round 5
// baseline (1403.709 us; speedup 1.0000x reference)
//
#include <hip/hip_runtime.h>

#define WALK 16
#define HID 64
#define CHUNK 16384
#define BSH 7          // bucket = 128 nodes
#define MAXB 808       // supports N <= 103424

// ===========================================================================
// Atomic-free CSR build (counting sort into 128-col buckets) + LDS-accumulated
// pull steps. Global atomics execute at the fabric (~20 G/s) regardless of
// scope (R3). R4's direct scatter had 4.8x write amplification (80B runs,
// 64-way split stores). R5: per-chunk LDS counting sort -> coalesced writes.
//
// ws layout (words):
//   csr    : 2E        uint2 {row | col_low<<25, ew_bits}, bucket-grouped
//   degp   : E         (tier A) (ew & ~127) | row_low, row-bucket-grouped
//   bptrc  : NBKT+1 | totc: NBKT | bptrr: NBKT+1 (A) | totr: NBKT (A)
//   dinv   : N | qA : N | qB : N
//   probs  : 16N       plane k = prob after step k+1
//            build overlay: Cc[NW*NBKT] (+Cr) per-chunk counts matrices
// ===========================================================================

// ---- per-chunk LDS histogram -> counts matrix C[w*NBKT+b] ----
__global__ __launch_bounds__(256) void hist_k(const int* __restrict__ ei,
                                              int* __restrict__ Cc,
                                              int* __restrict__ Cr,
                                              int NBKT, int E, int do_row) {
    __shared__ int cntc[MAXB];
    __shared__ int cntr[MAXB];
    int w = blockIdx.x, tid = threadIdx.x;
    for (int b = tid; b < NBKT; b += 256) { cntc[b] = 0; cntr[b] = 0; }
    __syncthreads();
    int s = w * CHUNK;
    int cnt = min(E - s, CHUNK);
    const int* colp = ei + E;
    int vec = ((E & 3) == 0) ? (cnt & ~3) : 0;
    for (int off = 4 * tid; off < vec; off += 1024) {
        int4 c4 = *(const int4*)(colp + s + off);
        atomicAdd(&cntc[c4.x >> BSH], 1);
        atomicAdd(&cntc[c4.y >> BSH], 1);
        atomicAdd(&cntc[c4.z >> BSH], 1);
        atomicAdd(&cntc[c4.w >> BSH], 1);
        if (do_row) {
            int4 r4 = *(const int4*)(ei + s + off);
            atomicAdd(&cntr[r4.x >> BSH], 1);
            atomicAdd(&cntr[r4.y >> BSH], 1);
            atomicAdd(&cntr[r4.z >> BSH], 1);
            atomicAdd(&cntr[r4.w >> BSH], 1);
        }
    }
    for (int off = vec + tid; off < cnt; off += 256) {
        atomicAdd(&cntc[colp[s + off] >> BSH], 1);
        if (do_row) atomicAdd(&cntr[ei[s + off] >> BSH], 1);
    }
    __syncthreads();
    for (int b = tid; b < NBKT; b += 256) {
        Cc[(size_t)w * NBKT + b] = cntc[b];
        if (do_row) Cr[(size_t)w * NBKT + b] = cntr[b];
    }
}

// ---- per-bucket prefix over chunks (in place); tot[b] = bucket total ----
__global__ __launch_bounds__(256) void colscan_k(int* __restrict__ C,
                                                 int* __restrict__ tot,
                                                 int NBKT, int NW) {
    int b = blockIdx.x * 256 + threadIdx.x;
    if (b >= NBKT) return;
    int run = 0;
    for (int w = 0; w < NW; ++w) {
        size_t idx = (size_t)w * NBKT + b;
        int t = C[idx];
        C[idx] = run;
        run += t;
    }
    tot[b] = run;
}

// ---- single-wg exclusive scan of bucket totals -> bptr; bptr[NBKT] = E ----
__global__ __launch_bounds__(1024) void bktscan_k(const int* __restrict__ tot,
                                                  int* __restrict__ ptr,
                                                  int NBKT, int E) {
    __shared__ int wsum[16];
    __shared__ int carry_s;
    int tid = threadIdx.x, lane = tid & 63, wid = tid >> 6;
    if (tid == 0) carry_s = 0;
    __syncthreads();
    for (int base = 0; base < NBKT; base += 1024) {
        int x = (base + tid < NBKT) ? tot[base + tid] : 0;
        int v = x;
        #pragma unroll
        for (int d = 1; d < 64; d <<= 1) { int t = __shfl_up(v, d); if (lane >= d) v += t; }
        __syncthreads();
        if (lane == 63) wsum[wid] = v;
        __syncthreads();
        if (tid < 16) {
            int sv = wsum[tid];
            #pragma unroll
            for (int d = 1; d < 16; d <<= 1) { int t = __shfl_up(sv, d); if (tid >= d) sv += t; }
            wsum[tid] = sv;
        }
        __syncthreads();
        int woff = wid ? wsum[wid - 1] : 0;
        int carry = carry_s;
        if (base + tid < NBKT) ptr[base + tid] = carry + woff + v - x;
        __syncthreads();
        if (tid == 0) carry_s = carry + wsum[15];
    }
    if (tid == 0) ptr[NBKT] = E;
}

// ---- per-chunk LDS counting sort, then coalesced global writes ----
__global__ __launch_bounds__(1024) void scatter_sort_k(const int* __restrict__ ei,
                                                       const float* __restrict__ ew,
                                                       const int* __restrict__ Cc,
                                                       const int* __restrict__ Cr,
                                                       const int* __restrict__ bptrc,
                                                       const int* __restrict__ bptrr,
                                                       uint2* __restrict__ csr,
                                                       unsigned* __restrict__ degp,
                                                       int NBKT, int E, int do_row) {
    __shared__ uint2 stg[CHUNK];                 // 128 KB staging
    __shared__ int cnt[MAXB];                    // hist, then insert cursor
    __shared__ int pfx[MAXB + 1];                // in-chunk bucket offsets
    __shared__ int rbs[MAXB];                    // global_base - pfx (dst = rbs[b]+j)
    __shared__ int wsum[16];
    unsigned* ustg = (unsigned*)stg;
    const int w = blockIdx.x, tid = threadIdx.x;
    const int lane = tid & 63, wid = tid >> 6;
    const int s = w * CHUNK;
    const int m = min(E - s, CHUNK);

    int rr[16], cc[16];
    unsigned wb[16];
    for (int b = tid; b < NBKT; b += 1024) cnt[b] = 0;
    __syncthreads();
    #pragma unroll
    for (int i = 0; i < 16; ++i) {
        int off = tid + i * 1024;
        bool ok = off < m;
        int r = 0, c = 0; float v = 0.0f;
        if (ok) { r = ei[s + off]; c = ei[E + s + off]; v = ew[s + off]; }
        rr[i] = r; cc[i] = c; wb[i] = __float_as_uint(v);
        if (ok) atomicAdd(&cnt[c >> BSH], 1);
    }
    __syncthreads();
    {   // block scan cols -> pfx; rbs = bptrc + Cc[w] - pfx; reset cursor
        int x = (tid < NBKT) ? cnt[tid] : 0;
        int v = x;
        #pragma unroll
        for (int d = 1; d < 64; d <<= 1) { int t = __shfl_up(v, d); if (lane >= d) v += t; }
        if (lane == 63) wsum[wid] = v;
        __syncthreads();
        if (tid < 16) {
            int sv = wsum[tid];
            #pragma unroll
            for (int d = 1; d < 16; d <<= 1) { int t = __shfl_up(sv, d); if (tid >= d) sv += t; }
            wsum[tid] = sv;
        }
        __syncthreads();
        int excl = (wid ? wsum[wid - 1] : 0) + v - x;
        if (tid < NBKT) {
            pfx[tid] = excl;
            rbs[tid] = bptrc[tid] + Cc[(size_t)w * NBKT + tid] - excl;
            cnt[tid] = 0;
        }
        if (tid == 0) pfx[NBKT] = m;
    }
    __syncthreads();
    #pragma unroll
    for (int i = 0; i < 16; ++i) {
        int off = tid + i * 1024;
        if (off < m) {
            int b = cc[i] >> BSH;
            int l = atomicAdd(&cnt[b], 1);
            stg[pfx[b] + l] = make_uint2((unsigned)rr[i] | ((unsigned)(cc[i] & 127) << 25), wb[i]);
        }
    }
    __syncthreads();
    for (int j = tid; j < m; j += 1024) {       // coalesced writeout
        int lo = 0, hi = NBKT;
        while (hi - lo > 1) { int mid = (lo + hi) >> 1; if (pfx[mid] <= j) lo = mid; else hi = mid; }
        csr[(size_t)(rbs[lo] + j)] = stg[j];
    }
    if (!do_row) return;
    __syncthreads();
    // ---- phase 2: rows -> degp (4B payload) ----
    for (int b = tid; b < NBKT; b += 1024) cnt[b] = 0;
    __syncthreads();
    #pragma unroll
    for (int i = 0; i < 16; ++i) {
        int off = tid + i * 1024;
        if (off < m) atomicAdd(&cnt[rr[i] >> BSH], 1);
    }
    __syncthreads();
    {
        int x = (tid < NBKT) ? cnt[tid] : 0;
        int v = x;
        #pragma unroll
        for (int d = 1; d < 64; d <<= 1) { int t = __shfl_up(v, d); if (lane >= d) v += t; }
        if (lane == 63) wsum[wid] = v;
        __syncthreads();
        if (tid < 16) {
            int sv = wsum[tid];
            #pragma unroll
            for (int d = 1; d < 16; d <<= 1) { int t = __shfl_up(sv, d); if (tid >= d) sv += t; }
            wsum[tid] = sv;
        }
        __syncthreads();
        int excl = (wid ? wsum[wid - 1] : 0) + v - x;
        if (tid < NBKT) {
            pfx[tid] = excl;
            rbs[tid] = bptrr[tid] + Cr[(size_t)w * NBKT + tid] - excl;
            cnt[tid] = 0;
        }
        if (tid == 0) pfx[NBKT] = m;
    }
    __syncthreads();
    #pragma unroll
    for (int i = 0; i < 16; ++i) {
        int off = tid + i * 1024;
        if (off < m) {
            int b = rr[i] >> BSH;
            int l = atomicAdd(&cnt[b], 1);
            ustg[pfx[b] + l] = (wb[i] & ~127u) | ((unsigned)rr[i] & 127u);
        }
    }
    __syncthreads();
    for (int j = tid; j < m; j += 1024) {
        int lo = 0, hi = NBKT;
        while (hi - lo > 1) { int mid = (lo + hi) >> 1; if (pfx[mid] <= j) lo = mid; else hi = mid; }
        degp[(size_t)(rbs[lo] + j)] = ustg[j];
    }
}

// ---- deg via LDS accumulation over row-buckets (tier A) ----
__global__ __launch_bounds__(256) void deg_k(const unsigned* __restrict__ degp,
                                             const int* __restrict__ bptrr,
                                             float* __restrict__ dinv,
                                             float* __restrict__ q0, int N) {
    __shared__ float acc[128];
    int rb = blockIdx.x, tid = threadIdx.x;
    if (tid < 128) acc[tid] = 0.0f;
    __syncthreads();
    int s = bptrr[rb], e = bptrr[rb + 1];
    int i = s + tid;
    for (; i + 768 < e; i += 1024) {
        unsigned p0 = degp[i], p1 = degp[i + 256], p2 = degp[i + 512], p3 = degp[i + 768];
        atomicAdd(&acc[p0 & 127], __uint_as_float(p0 & ~127u));
        atomicAdd(&acc[p1 & 127], __uint_as_float(p1 & ~127u));
        atomicAdd(&acc[p2 & 127], __uint_as_float(p2 & ~127u));
        atomicAdd(&acc[p3 & 127], __uint_as_float(p3 & ~127u));
    }
    for (; i < e; i += 256) {
        unsigned p = degp[i];
        atomicAdd(&acc[p & 127], __uint_as_float(p & ~127u));
    }
    __syncthreads();
    if (tid < 128) {
        int r = rb * 128 + tid;
        if (r < N) {
            float dv = 1.0f / fmaxf(acc[tid] + 1.0f, 1e-8f);  // +1 self-loop
            dinv[r] = dv;
            q0[r] = dv;
        }
    }
}

// ---- tier B deg: fabric atomics + inverse ----
__global__ __launch_bounds__(256) void dega_k(const int* __restrict__ ei,
                                              const float* __restrict__ ew,
                                              float* __restrict__ deg, int E) {
    int e = blockIdx.x * 256 + threadIdx.x;
    if (e < E) atomicAdd(&deg[ei[e]], ew[e]);
}

__global__ __launch_bounds__(256) void inv_k(const float* __restrict__ deg,
                                             float* __restrict__ dinv,
                                             float* __restrict__ q0, int N) {
    int i = blockIdx.x * 256 + threadIdx.x;
    if (i < N) {
        float dv = 1.0f / fmaxf(deg[i] + 1.0f, 1e-8f);
        dinv[i] = dv;
        q0[i] = dv;
    }
}

// ---- one step: per col-bucket LDS accumulate, 8-deep gather pipeline ----
__global__ __launch_bounds__(256) void step_k(const uint2* __restrict__ csr,
                                              const int* __restrict__ bptrc,
                                              const float* __restrict__ q,
                                              const float* __restrict__ dinv,
                                              float* __restrict__ prob_out,
                                              float* __restrict__ q_out, int N) {
    __shared__ float acc[128];
    int cb = blockIdx.x, tid = threadIdx.x;
    if (tid < 128) acc[tid] = 0.0f;
    __syncthreads();
    int s = bptrc[cb], e = bptrc[cb + 1];
    int i = s + tid;
    for (; i + 1792 < e; i += 2048) {
        uint2 t0 = csr[i], t1 = csr[i + 256], t2 = csr[i + 512], t3 = csr[i + 768];
        uint2 t4 = csr[i + 1024], t5 = csr[i + 1280], t6 = csr[i + 1536], t7 = csr[i + 1792];
        float v0 = q[t0.x & 0x1FFFFFF] * __uint_as_float(t0.y);
        float v1 = q[t1.x & 0x1FFFFFF] * __uint_as_float(t1.y);
        float v2 = q[t2.x & 0x1FFFFFF] * __uint_as_float(t2.y);
        float v3 = q[t3.x & 0x1FFFFFF] * __uint_as_float(t3.y);
        float v4 = q[t4.x & 0x1FFFFFF] * __uint_as_float(t4.y);
        float v5 = q[t5.x & 0x1FFFFFF] * __uint_as_float(t5.y);
        float v6 = q[t6.x & 0x1FFFFFF] * __uint_as_float(t6.y);
        float v7 = q[t7.x & 0x1FFFFFF] * __uint_as_float(t7.y);
        atomicAdd(&acc[t0.x >> 25], v0);
        atomicAdd(&acc[t1.x >> 25], v1);
        atomicAdd(&acc[t2.x >> 25], v2);
        atomicAdd(&acc[t3.x >> 25], v3);
        atomicAdd(&acc[t4.x >> 25], v4);
        atomicAdd(&acc[t5.x >> 25], v5);
        atomicAdd(&acc[t6.x >> 25], v6);
        atomicAdd(&acc[t7.x >> 25], v7);
    }
    for (; i < e; i += 256) {
        uint2 t = csr[i];
        atomicAdd(&acc[t.x >> 25], q[t.x & 0x1FFFFFF] * __uint_as_float(t.y));
    }
    __syncthreads();
    if (tid < 128) {
        int c = cb * 128 + tid;
        if (c < N) {
            float p = acc[tid] + q[c];   // self-loop: prob[c]*dinv[c] = q[c]
            prob_out[c] = p;
            q_out[c] = p * dinv[c];
        }
    }
}

// ---- per-node MLP ----
__global__ __launch_bounds__(256) void mlp_kernel(const float* __restrict__ probs,
                                                  const float* __restrict__ W1,
                                                  const float* __restrict__ b1,
                                                  const float* __restrict__ W2,
                                                  const float* __restrict__ b2,
                                                  float* __restrict__ out, int N) {
    __shared__ float W1s[HID * WALK];
    __shared__ float W2s[HID * HID];
    __shared__ float b1s[HID], b2s[HID];
    int tid = threadIdx.x;
    for (int i = tid; i < HID * WALK; i += 256) W1s[i] = W1[i];
    for (int i = tid; i < HID * HID; i += 256) W2s[i] = W2[i];
    if (tid < HID) { b1s[tid] = b1[tid]; b2s[tid] = b2[tid]; }
    __syncthreads();

    int n = blockIdx.x * 256 + tid;
    if (n >= N) return;

    float p[WALK];
    #pragma unroll
    for (int k = 0; k < WALK; ++k) p[k] = probs[(size_t)k * N + n];

    float h[HID];
    #pragma unroll
    for (int j = 0; j < HID; ++j) {
        float a = b1s[j];
        #pragma unroll
        for (int k = 0; k < WALK; ++k) a += W1s[j * WALK + k] * p[k];
        h[j] = fmaxf(a, 0.0f);
    }

    #pragma unroll
    for (int j = 0; j < HID; j += 4) {
        float4 o;
        float* op = (float*)&o;
        #pragma unroll
        for (int qq = 0; qq < 4; ++qq) {
            float a = b2s[j + qq];
            #pragma unroll
            for (int k = 0; k < HID; ++k) a += W2s[(j + qq) * HID + k] * h[k];
            op[qq] = a;
        }
        *(float4*)&out[(size_t)n * HID + j] = o;
    }
}

// ---- last-resort push fallback ----
__global__ __launch_bounds__(256) void init_push(float* __restrict__ probs, int N) {
    int i = blockIdx.x * 256 + threadIdx.x;
    if (i < N) {
        probs[i] = 1.0f;
        #pragma unroll
        for (int k = 1; k <= WALK; ++k) probs[(size_t)k * N + i] = 0.0f;
    }
}

__global__ __launch_bounds__(256) void step_push(const int* __restrict__ ei,
                                                 const float* __restrict__ ew,
                                                 const float* __restrict__ dinv,
                                                 const float* __restrict__ src,
                                                 float* __restrict__ dst,
                                                 int E, int N) {
    int idx = blockIdx.x * 256 + threadIdx.x;
    if (idx < E) {
        int r = ei[idx], c = ei[E + idx];
        atomicAdd(&dst[c], src[r] * ew[idx] * dinv[r]);
    } else if (idx < E + N) {
        int i = idx - E;
        atomicAdd(&dst[i], src[i] * dinv[i]);
    }
}

// ---- launch ----
extern "C" void kernel_launch(void* const* d_in, const int* in_sizes, int n_in,
                              void* d_out, int out_size, void* d_ws, size_t ws_size,
                              hipStream_t stream) {
    const int*   ei = (const int*)d_in[0];
    const float* ew = (const float*)d_in[2];
    const float* W1 = (const float*)d_in[3];
    const float* b1 = (const float*)d_in[4];
    const float* W2 = (const float*)d_in[5];
    const float* b2 = (const float*)d_in[6];
    const int E = in_sizes[2];
    const int N = out_size / HID;
    float* out = (float*)d_out;

    const int NB   = (N + 255) / 256;
    const int NBKT = (N + 127) / 128;
    const int NW   = (E + CHUNK - 1) / CHUNK;

    size_t wordsB = (size_t)2 * E + 2 * (size_t)NBKT + 1 + 19 * (size_t)N + 64;
    size_t wordsA = wordsB + (size_t)E + 2 * (size_t)NBKT + 1;
    bool overlay_ok = (size_t)2 * NW * NBKT <= (size_t)16 * N;
    bool okA = NBKT <= MAXB && overlay_ok && ws_size >= wordsA * 4;
    bool okB = NBKT <= MAXB && ((size_t)NW * NBKT <= (size_t)16 * N) && ws_size >= wordsB * 4;

    if (okA || okB) {
        char* p = (char*)d_ws;
        uint2* csr = (uint2*)p;              p += (size_t)E * 8;
        unsigned* degp = nullptr;
        if (okA) { degp = (unsigned*)p;      p += (size_t)E * 4; }
        int* bptrc = (int*)p;                p += (size_t)(NBKT + 1) * 4;
        int* totc  = (int*)p;                p += (size_t)NBKT * 4;
        int* bptrr = nullptr; int* totr = nullptr;
        if (okA) {
            bptrr = (int*)p;                 p += (size_t)(NBKT + 1) * 4;
            totr  = (int*)p;                 p += (size_t)NBKT * 4;
        }
        float* dinv = (float*)p;             p += (size_t)N * 4;
        float* qA   = (float*)p;             p += (size_t)N * 4;
        float* qB   = (float*)p;             p += (size_t)N * 4;
        float* probs = (float*)p;
        int* Cc = (int*)probs;               // overlay, dead before steps
        int* Cr = Cc + (size_t)NW * NBKT;

        hist_k<<<NW, 256, 0, stream>>>(ei, Cc, Cr, NBKT, E, okA ? 1 : 0);
        colscan_k<<<(NBKT + 255) / 256, 256, 0, stream>>>(Cc, totc, NBKT, NW);
        bktscan_k<<<1, 1024, 0, stream>>>(totc, bptrc, NBKT, E);
        if (okA) {
            colscan_k<<<(NBKT + 255) / 256, 256, 0, stream>>>(Cr, totr, NBKT, NW);
            bktscan_k<<<1, 1024, 0, stream>>>(totr, bptrr, NBKT, E);
        }
        scatter_sort_k<<<NW, 1024, 0, stream>>>(ei, ew, Cc, Cr, bptrc, bptrr,
                                                csr, degp, NBKT, E, okA ? 1 : 0);
        if (okA) {
            deg_k<<<NBKT, 256, 0, stream>>>(degp, bptrr, dinv, qA, N);
        } else {
            hipMemsetAsync(qB, 0, (size_t)N * 4, stream);
            dega_k<<<(E + 255) / 256, 256, 0, stream>>>(ei, ew, qB, E);
            inv_k<<<NB, 256, 0, stream>>>(qB, dinv, qA, N);
        }

        float* qs = qA; float* qd = qB;
        for (int k = 0; k < WALK; ++k) {
            step_k<<<NBKT, 256, 0, stream>>>(csr, bptrc, qs, dinv,
                                             probs + (size_t)k * N, qd, N);
            float* t = qs; qs = qd; qd = t;
        }
        mlp_kernel<<<NB, 256, 0, stream>>>(probs, W1, b1, W2, b2, out, N);
    } else {
        float* deg   = (float*)d_ws;
        float* dinv  = deg + N;
        float* probs = dinv + N;
        hipMemsetAsync(deg, 0, (size_t)N * 4, stream);
        init_push<<<NB, 256, 0, stream>>>(probs, N);
        dega_k<<<(E + 255) / 256, 256, 0, stream>>>(ei, ew, deg, E);
        inv_k<<<NB, 256, 0, stream>>>(deg, dinv, dinv, N);
        for (int k = 0; k < WALK; ++k) {
            step_push<<<(E + N + 255) / 256, 256, 0, stream>>>(
                ei, ew, dinv, probs + (size_t)k * N, probs + (size_t)(k + 1) * N, E, N);
        }
        mlp_kernel<<<NB, 256, 0, stream>>>(probs + N, W1, b1, W2, b2, out, N);
    }
}

// Round 6
// 1284.277 us; speedup vs baseline: 1.0930x; 1.0930x over previous
//
#include <hip/hip_runtime.h>

#define WALK 16
#define HID 64
#define CHUNK 16384
#define BSH 7          // bucket = 128 nodes
#define MAXB 808       // supports N <= 103424

// ===========================================================================
// Atomic-free CSR build (counting sort into 128-col buckets) + LDS-accumulated
// pull steps. Global atomics execute at the fabric (~20 G/s) regardless of
// scope (R3). R4 scatter had 4.8x write amplification -> R5 LDS counting sort.
// R6: MLP reads weights via uniform global loads (s_load -> SGPR-broadcast
// FMA), replacing 5120 ds_read_b32 broadcasts per thread (R5: 182 us,
// VALUBusy 10.8%, LDS-throughput-bound).
//
// ws layout (words):
//   csr    : 2E        uint2 {row | col_low<<25, ew_bits}, bucket-grouped
//   degp   : E         (tier A) (ew & ~127) | row_low, row-bucket-grouped
//   bptrc  : NBKT+1 | totc: NBKT | bptrr: NBKT+1 (A) | totr: NBKT (A)
//   dinv   : N | qA : N | qB : N
//   probs  : 16N       plane k = prob after step k+1
//            build overlay: Cc[NW*NBKT] (+Cr) per-chunk counts matrices
// ===========================================================================

// ---- per-chunk LDS histogram -> counts matrix C[w*NBKT+b] ----
__global__ __launch_bounds__(256) void hist_k(const int* __restrict__ ei,
                                              int* __restrict__ Cc,
                                              int* __restrict__ Cr,
                                              int NBKT, int E, int do_row) {
    __shared__ int cntc[MAXB];
    __shared__ int cntr[MAXB];
    int w = blockIdx.x, tid = threadIdx.x;
    for (int b = tid; b < NBKT; b += 256) { cntc[b] = 0; cntr[b] = 0; }
    __syncthreads();
    int s = w * CHUNK;
    int cnt = min(E - s, CHUNK);
    const int* colp = ei + E;
    int vec = ((E & 3) == 0) ? (cnt & ~3) : 0;
    for (int off = 4 * tid; off < vec; off += 1024) {
        int4 c4 = *(const int4*)(colp + s + off);
        atomicAdd(&cntc[c4.x >> BSH], 1);
        atomicAdd(&cntc[c4.y >> BSH], 1);
        atomicAdd(&cntc[c4.z >> BSH], 1);
        atomicAdd(&cntc[c4.w >> BSH], 1);
        if (do_row) {
            int4 r4 = *(const int4*)(ei + s + off);
            atomicAdd(&cntr[r4.x >> BSH], 1);
            atomicAdd(&cntr[r4.y >> BSH], 1);
            atomicAdd(&cntr[r4.z >> BSH], 1);
            atomicAdd(&cntr[r4.w >> BSH], 1);
        }
    }
    for (int off = vec + tid; off < cnt; off += 256) {
        atomicAdd(&cntc[colp[s + off] >> BSH], 1);
        if (do_row) atomicAdd(&cntr[ei[s + off] >> BSH], 1);
    }
    __syncthreads();
    for (int b = tid; b < NBKT; b += 256) {
        Cc[(size_t)w * NBKT + b] = cntc[b];
        if (do_row) Cr[(size_t)w * NBKT + b] = cntr[b];
    }
}

// ---- per-bucket prefix over chunks (in place); tot[b] = bucket total ----
__global__ __launch_bounds__(256) void colscan_k(int* __restrict__ C,
                                                 int* __restrict__ tot,
                                                 int NBKT, int NW) {
    int b = blockIdx.x * 256 + threadIdx.x;
    if (b >= NBKT) return;
    int run = 0;
    for (int w = 0; w < NW; ++w) {
        size_t idx = (size_t)w * NBKT + b;
        int t = C[idx];
        C[idx] = run;
        run += t;
    }
    tot[b] = run;
}

// ---- single-wg exclusive scan of bucket totals -> bptr; bptr[NBKT] = E ----
__global__ __launch_bounds__(1024) void bktscan_k(const int* __restrict__ tot,
                                                  int* __restrict__ ptr,
                                                  int NBKT, int E) {
    __shared__ int wsum[16];
    __shared__ int carry_s;
    int tid = threadIdx.x, lane = tid & 63, wid = tid >> 6;
    if (tid == 0) carry_s = 0;
    __syncthreads();
    for (int base = 0; base < NBKT; base += 1024) {
        int x = (base + tid < NBKT) ? tot[base + tid] : 0;
        int v = x;
        #pragma unroll
        for (int d = 1; d < 64; d <<= 1) { int t = __shfl_up(v, d); if (lane >= d) v += t; }
        __syncthreads();
        if (lane == 63) wsum[wid] = v;
        __syncthreads();
        if (tid < 16) {
            int sv = wsum[tid];
            #pragma unroll
            for (int d = 1; d < 16; d <<= 1) { int t = __shfl_up(sv, d); if (tid >= d) sv += t; }
            wsum[tid] = sv;
        }
        __syncthreads();
        int woff = wid ? wsum[wid - 1] : 0;
        int carry = carry_s;
        if (base + tid < NBKT) ptr[base + tid] = carry + woff + v - x;
        __syncthreads();
        if (tid == 0) carry_s = carry + wsum[15];
    }
    if (tid == 0) ptr[NBKT] = E;
}

// ---- per-chunk LDS counting sort, then coalesced global writes ----
__global__ __launch_bounds__(1024) void scatter_sort_k(const int* __restrict__ ei,
                                                       const float* __restrict__ ew,
                                                       const int* __restrict__ Cc,
                                                       const int* __restrict__ Cr,
                                                       const int* __restrict__ bptrc,
                                                       const int* __restrict__ bptrr,
                                                       uint2* __restrict__ csr,
                                                       unsigned* __restrict__ degp,
                                                       int NBKT, int E, int do_row) {
    __shared__ uint2 stg[CHUNK];                 // 128 KB staging
    __shared__ int cnt[MAXB];                    // hist, then insert cursor
    __shared__ int pfx[MAXB + 1];                // in-chunk bucket offsets
    __shared__ int rbs[MAXB];                    // global_base - pfx (dst = rbs[b]+j)
    __shared__ int wsum[16];
    unsigned* ustg = (unsigned*)stg;
    const int w = blockIdx.x, tid = threadIdx.x;
    const int lane = tid & 63, wid = tid >> 6;
    const int s = w * CHUNK;
    const int m = min(E - s, CHUNK);

    int rr[16], cc[16];
    unsigned wb[16];
    for (int b = tid; b < NBKT; b += 1024) cnt[b] = 0;
    __syncthreads();
    #pragma unroll
    for (int i = 0; i < 16; ++i) {
        int off = tid + i * 1024;
        bool ok = off < m;
        int r = 0, c = 0; float v = 0.0f;
        if (ok) { r = ei[s + off]; c = ei[E + s + off]; v = ew[s + off]; }
        rr[i] = r; cc[i] = c; wb[i] = __float_as_uint(v);
        if (ok) atomicAdd(&cnt[c >> BSH], 1);
    }
    __syncthreads();
    {   // block scan cols -> pfx; rbs = bptrc + Cc[w] - pfx; reset cursor
        int x = (tid < NBKT) ? cnt[tid] : 0;
        int v = x;
        #pragma unroll
        for (int d = 1; d < 64; d <<= 1) { int t = __shfl_up(v, d); if (lane >= d) v += t; }
        if (lane == 63) wsum[wid] = v;
        __syncthreads();
        if (tid < 16) {
            int sv = wsum[tid];
            #pragma unroll
            for (int d = 1; d < 16; d <<= 1) { int t = __shfl_up(sv, d); if (tid >= d) sv += t; }
            wsum[tid] = sv;
        }
        __syncthreads();
        int excl = (wid ? wsum[wid - 1] : 0) + v - x;
        if (tid < NBKT) {
            pfx[tid] = excl;
            rbs[tid] = bptrc[tid] + Cc[(size_t)w * NBKT + tid] - excl;
            cnt[tid] = 0;
        }
        if (tid == 0) pfx[NBKT] = m;
    }
    __syncthreads();
    #pragma unroll
    for (int i = 0; i < 16; ++i) {
        int off = tid + i * 1024;
        if (off < m) {
            int b = cc[i] >> BSH;
            int l = atomicAdd(&cnt[b], 1);
            stg[pfx[b] + l] = make_uint2((unsigned)rr[i] | ((unsigned)(cc[i] & 127) << 25), wb[i]);
        }
    }
    __syncthreads();
    for (int j = tid; j < m; j += 1024) {       // coalesced writeout
        int lo = 0, hi = NBKT;
        while (hi - lo > 1) { int mid = (lo + hi) >> 1; if (pfx[mid] <= j) lo = mid; else hi = mid; }
        csr[(size_t)(rbs[lo] + j)] = stg[j];
    }
    if (!do_row) return;
    __syncthreads();
    // ---- phase 2: rows -> degp (4B payload) ----
    for (int b = tid; b < NBKT; b += 1024) cnt[b] = 0;
    __syncthreads();
    #pragma unroll
    for (int i = 0; i < 16; ++i) {
        int off = tid + i * 1024;
        if (off < m) atomicAdd(&cnt[rr[i] >> BSH], 1);
    }
    __syncthreads();
    {
        int x = (tid < NBKT) ? cnt[tid] : 0;
        int v = x;
        #pragma unroll
        for (int d = 1; d < 64; d <<= 1) { int t = __shfl_up(v, d); if (lane >= d) v += t; }
        if (lane == 63) wsum[wid] = v;
        __syncthreads();
        if (tid < 16) {
            int sv = wsum[tid];
            #pragma unroll
            for (int d = 1; d < 16; d <<= 1) { int t = __shfl_up(sv, d); if (tid >= d) sv += t; }
            wsum[tid] = sv;
        }
        __syncthreads();
        int excl = (wid ? wsum[wid - 1] : 0) + v - x;
        if (tid < NBKT) {
            pfx[tid] = excl;
            rbs[tid] = bptrr[tid] + Cr[(size_t)w * NBKT + tid] - excl;
            cnt[tid] = 0;
        }
        if (tid == 0) pfx[NBKT] = m;
    }
    __syncthreads();
    #pragma unroll
    for (int i = 0; i < 16; ++i) {
        int off = tid + i * 1024;
        if (off < m) {
            int b = rr[i] >> BSH;
            int l = atomicAdd(&cnt[b], 1);
            ustg[pfx[b] + l] = (wb[i] & ~127u) | ((unsigned)rr[i] & 127u);
        }
    }
    __syncthreads();
    for (int j = tid; j < m; j += 1024) {
        int lo = 0, hi = NBKT;
        while (hi - lo > 1) { int mid = (lo + hi) >> 1; if (pfx[mid] <= j) lo = mid; else hi = mid; }
        degp[(size_t)(rbs[lo] + j)] = ustg[j];
    }
}

// ---- deg via LDS accumulation over row-buckets (tier A) ----
__global__ __launch_bounds__(256) void deg_k(const unsigned* __restrict__ degp,
                                             const int* __restrict__ bptrr,
                                             float* __restrict__ dinv,
                                             float* __restrict__ q0, int N) {
    __shared__ float acc[128];
    int rb = blockIdx.x, tid = threadIdx.x;
    if (tid < 128) acc[tid] = 0.0f;
    __syncthreads();
    int s = bptrr[rb], e = bptrr[rb + 1];
    int i = s + tid;
    for (; i + 768 < e; i += 1024) {
        unsigned p0 = degp[i], p1 = degp[i + 256], p2 = degp[i + 512], p3 = degp[i + 768];
        atomicAdd(&acc[p0 & 127], __uint_as_float(p0 & ~127u));
        atomicAdd(&acc[p1 & 127], __uint_as_float(p1 & ~127u));
        atomicAdd(&acc[p2 & 127], __uint_as_float(p2 & ~127u));
        atomicAdd(&acc[p3 & 127], __uint_as_float(p3 & ~127u));
    }
    for (; i < e; i += 256) {
        unsigned p = degp[i];
        atomicAdd(&acc[p & 127], __uint_as_float(p & ~127u));
    }
    __syncthreads();
    if (tid < 128) {
        int r = rb * 128 + tid;
        if (r < N) {
            float dv = 1.0f / fmaxf(acc[tid] + 1.0f, 1e-8f);  // +1 self-loop
            dinv[r] = dv;
            q0[r] = dv;
        }
    }
}

// ---- tier B deg: fabric atomics + inverse ----
__global__ __launch_bounds__(256) void dega_k(const int* __restrict__ ei,
                                              const float* __restrict__ ew,
                                              float* __restrict__ deg, int E) {
    int e = blockIdx.x * 256 + threadIdx.x;
    if (e < E) atomicAdd(&deg[ei[e]], ew[e]);
}

__global__ __launch_bounds__(256) void inv_k(const float* __restrict__ deg,
                                             float* __restrict__ dinv,
                                             float* __restrict__ q0, int N) {
    int i = blockIdx.x * 256 + threadIdx.x;
    if (i < N) {
        float dv = 1.0f / fmaxf(deg[i] + 1.0f, 1e-8f);
        dinv[i] = dv;
        q0[i] = dv;
    }
}

// ---- one step: per col-bucket LDS accumulate, 8-deep gather pipeline ----
__global__ __launch_bounds__(256) void step_k(const uint2* __restrict__ csr,
                                              const int* __restrict__ bptrc,
                                              const float* __restrict__ q,
                                              const float* __restrict__ dinv,
                                              float* __restrict__ prob_out,
                                              float* __restrict__ q_out, int N) {
    __shared__ float acc[128];
    int cb = blockIdx.x, tid = threadIdx.x;
    if (tid < 128) acc[tid] = 0.0f;
    __syncthreads();
    int s = bptrc[cb], e = bptrc[cb + 1];
    int i = s + tid;
    for (; i + 1792 < e; i += 2048) {
        uint2 t0 = csr[i], t1 = csr[i + 256], t2 = csr[i + 512], t3 = csr[i + 768];
        uint2 t4 = csr[i + 1024], t5 = csr[i + 1280], t6 = csr[i + 1536], t7 = csr[i + 1792];
        float v0 = q[t0.x & 0x1FFFFFF] * __uint_as_float(t0.y);
        float v1 = q[t1.x & 0x1FFFFFF] * __uint_as_float(t1.y);
        float v2 = q[t2.x & 0x1FFFFFF] * __uint_as_float(t2.y);
        float v3 = q[t3.x & 0x1FFFFFF] * __uint_as_float(t3.y);
        float v4 = q[t4.x & 0x1FFFFFF] * __uint_as_float(t4.y);
        float v5 = q[t5.x & 0x1FFFFFF] * __uint_as_float(t5.y);
        float v6 = q[t6.x & 0x1FFFFFF] * __uint_as_float(t6.y);
        float v7 = q[t7.x & 0x1FFFFFF] * __uint_as_float(t7.y);
        atomicAdd(&acc[t0.x >> 25], v0);
        atomicAdd(&acc[t1.x >> 25], v1);
        atomicAdd(&acc[t2.x >> 25], v2);
        atomicAdd(&acc[t3.x >> 25], v3);
        atomicAdd(&acc[t4.x >> 25], v4);
        atomicAdd(&acc[t5.x >> 25], v5);
        atomicAdd(&acc[t6.x >> 25], v6);
        atomicAdd(&acc[t7.x >> 25], v7);
    }
    for (; i < e; i += 256) {
        uint2 t = csr[i];
        atomicAdd(&acc[t.x >> 25], q[t.x & 0x1FFFFFF] * __uint_as_float(t.y));
    }
    __syncthreads();
    if (tid < 128) {
        int c = cb * 128 + tid;
        if (c < N) {
            float p = acc[tid] + q[c];   // self-loop: prob[c]*dinv[c] = q[c]
            prob_out[c] = p;
            q_out[c] = p * dinv[c];
        }
    }
}

// ---- per-node MLP: weights via uniform global loads (s_load/SGPR-broadcast),
//      no LDS. R5's LDS version issued 5120 ds_read_b32 per thread. ----
__global__ __launch_bounds__(128) void mlp2_kernel(const float* __restrict__ probs,
                                                   const float* __restrict__ W1,
                                                   const float* __restrict__ b1,
                                                   const float* __restrict__ W2,
                                                   const float* __restrict__ b2,
                                                   float* __restrict__ out, int N) {
    int n = blockIdx.x * 128 + threadIdx.x;
    if (n >= N) return;

    float p[WALK];
    #pragma unroll
    for (int k = 0; k < WALK; ++k) p[k] = probs[(size_t)k * N + n];

    float h[HID];
    #pragma unroll
    for (int j = 0; j < HID; ++j) {
        float a = b1[j];
        #pragma unroll
        for (int k = 0; k < WALK; ++k) a += W1[j * WALK + k] * p[k];
        h[j] = fmaxf(a, 0.0f);
    }

    #pragma unroll
    for (int j = 0; j < HID; j += 4) {
        float4 o;
        float* op = (float*)&o;
        #pragma unroll
        for (int qq = 0; qq < 4; ++qq) {
            float a = b2[j + qq];
            #pragma unroll
            for (int k = 0; k < HID; ++k) a += W2[(j + qq) * HID + k] * h[k];
            op[qq] = a;
        }
        *(float4*)&out[(size_t)n * HID + j] = o;
    }
}

// ---- last-resort push fallback ----
__global__ __launch_bounds__(256) void init_push(float* __restrict__ probs, int N) {
    int i = blockIdx.x * 256 + threadIdx.x;
    if (i < N) {
        probs[i] = 1.0f;
        #pragma unroll
        for (int k = 1; k <= WALK; ++k) probs[(size_t)k * N + i] = 0.0f;
    }
}

__global__ __launch_bounds__(256) void step_push(const int* __restrict__ ei,
                                                 const float* __restrict__ ew,
                                                 const float* __restrict__ dinv,
                                                 const float* __restrict__ src,
                                                 float* __restrict__ dst,
                                                 int E, int N) {
    int idx = blockIdx.x * 256 + threadIdx.x;
    if (idx < E) {
        int r = ei[idx], c = ei[E + idx];
        atomicAdd(&dst[c], src[r] * ew[idx] * dinv[r]);
    } else if (idx < E + N) {
        int i = idx - E;
        atomicAdd(&dst[i], src[i] * dinv[i]);
    }
}

// ---- launch ----
extern "C" void kernel_launch(void* const* d_in, const int* in_sizes, int n_in,
                              void* d_out, int out_size, void* d_ws, size_t ws_size,
                              hipStream_t stream) {
    const int*   ei = (const int*)d_in[0];
    const float* ew = (const float*)d_in[2];
    const float* W1 = (const float*)d_in[3];
    const float* b1 = (const float*)d_in[4];
    const float* W2 = (const float*)d_in[5];
    const float* b2 = (const float*)d_in[6];
    const int E = in_sizes[2];
    const int N = out_size / HID;
    float* out = (float*)d_out;

    const int NB   = (N + 255) / 256;
    const int NBM  = (N + 127) / 128;
    const int NBKT = (N + 127) / 128;
    const int NW   = (E + CHUNK - 1) / CHUNK;

    size_t wordsB = (size_t)2 * E + 2 * (size_t)NBKT + 1 + 19 * (size_t)N + 64;
    size_t wordsA = wordsB + (size_t)E + 2 * (size_t)NBKT + 1;
    bool overlay_ok = (size_t)2 * NW * NBKT <= (size_t)16 * N;
    bool okA = NBKT <= MAXB && overlay_ok && ws_size >= wordsA * 4;
    bool okB = NBKT <= MAXB && ((size_t)NW * NBKT <= (size_t)16 * N) && ws_size >= wordsB * 4;

    if (okA || okB) {
        char* p = (char*)d_ws;
        uint2* csr = (uint2*)p;              p += (size_t)E * 8;
        unsigned* degp = nullptr;
        if (okA) { degp = (unsigned*)p;      p += (size_t)E * 4; }
        int* bptrc = (int*)p;                p += (size_t)(NBKT + 1) * 4;
        int* totc  = (int*)p;                p += (size_t)NBKT * 4;
        int* bptrr = nullptr; int* totr = nullptr;
        if (okA) {
            bptrr = (int*)p;                 p += (size_t)(NBKT + 1) * 4;
            totr  = (int*)p;                 p += (size_t)NBKT * 4;
        }
        float* dinv = (float*)p;             p += (size_t)N * 4;
        float* qA   = (float*)p;             p += (size_t)N * 4;
        float* qB   = (float*)p;             p += (size_t)N * 4;
        float* probs = (float*)p;
        int* Cc = (int*)probs;               // overlay, dead before steps
        int* Cr = Cc + (size_t)NW * NBKT;

        hist_k<<<NW, 256, 0, stream>>>(ei, Cc, Cr, NBKT, E, okA ? 1 : 0);
        colscan_k<<<(NBKT + 255) / 256, 256, 0, stream>>>(Cc, totc, NBKT, NW);
        bktscan_k<<<1, 1024, 0, stream>>>(totc, bptrc, NBKT, E);
        if (okA) {
            colscan_k<<<(NBKT + 255) / 256, 256, 0, stream>>>(Cr, totr, NBKT, NW);
            bktscan_k<<<1, 1024, 0, stream>>>(totr, bptrr, NBKT, E);
        }
        scatter_sort_k<<<NW, 1024, 0, stream>>>(ei, ew, Cc, Cr, bptrc, bptrr,
                                                csr, degp, NBKT, E, okA ? 1 : 0);
        if (okA) {
            deg_k<<<NBKT, 256, 0, stream>>>(degp, bptrr, dinv, qA, N);
        } else {
            hipMemsetAsync(qB, 0, (size_t)N * 4, stream);
            dega_k<<<(E + 255) / 256, 256, 0, stream>>>(ei, ew, qB, E);
            inv_k<<<NB, 256, 0, stream>>>(qB, dinv, qA, N);
        }

        float* qs = qA; float* qd = qB;
        for (int k = 0; k < WALK; ++k) {
            step_k<<<NBKT, 256, 0, stream>>>(csr, bptrc, qs, dinv,
                                             probs + (size_t)k * N, qd, N);
            float* t = qs; qs = qd; qd = t;
        }
        mlp2_kernel<<<NBM, 128, 0, stream>>>(probs, W1, b1, W2, b2, out, N);
    } else {
        float* deg   = (float*)d_ws;
        float* dinv  = deg + N;
        float* probs = dinv + N;
        hipMemsetAsync(deg, 0, (size_t)N * 4, stream);
        init_push<<<NB, 256, 0, stream>>>(probs, N);
        dega_k<<<(E + 255) / 256, 256, 0, stream>>>(ei, ew, deg, E);
        inv_k<<<NB, 256, 0, stream>>>(deg, dinv, dinv, N);
        for (int k = 0; k < WALK; ++k) {
            step_push<<<(E + N + 255) / 256, 256, 0, stream>>>(
                ei, ew, dinv, probs + (size_t)k * N, probs + (size_t)(k + 1) * N, E, N);
        }
        mlp2_kernel<<<NBM, 128, 0, stream>>>(probs + N, W1, b1, W2, b2, out, N);
    }
}